// Round 1
// baseline (15324.783 us; speedup 1.0000x reference)
//
#include <hip/hip_runtime.h>
#include <math.h>

#define NSWEEP 14
#define SA 129   // padded LDS column stride (floats) -> conflict-free column access

// ---------------------------------------------------------------------------
// Kernel 1: collapse feature-weighting + conv chain into affine coef[29], c0.
// ---------------------------------------------------------------------------
__global__ void ssvd_coef_kernel(const float* __restrict__ c1w, const float* __restrict__ c1b,
                                 const float* __restrict__ c2w, const float* __restrict__ c2b,
                                 float* __restrict__ coefO) {
  if (threadIdx.x != 0 || blockIdx.x != 0) return;
  float cur[6][30], nxt[6][30];
  for (int i = 0; i < 6; ++i)
    for (int d = 0; d < 30; ++d) { cur[i][d] = 0.f; nxt[i][d] = 0.f; }
  const int FS[6] = {5, 5, 3, 8, 6, 2};
  int p = 0;
  for (int f = 0; f < 6; ++f) {
    for (int j = 0; j < FS[f]; ++j) cur[f][p + j] = (float)j;
    p += FS[f];
  }
  int len = 6;
  for (int rep = 0; rep < 3; ++rep) {       // conv1 x3: K=4, stride=2, pad=2
    int ol = len / 2 + 1;
    for (int t = 0; t < ol; ++t) {
      for (int d = 0; d < 30; ++d) {
        float acc = 0.f;
        for (int kk = 0; kk < 4; ++kk) {
          int ix = 2 * t - 2 + kk;
          if (ix >= 0 && ix < len) acc += cur[ix][d] * c1w[kk];
        }
        nxt[t][d] = acc;
      }
      nxt[t][29] += c1b[0];
    }
    for (int t = 0; t < ol; ++t)
      for (int d = 0; d < 30; ++d) cur[t][d] = nxt[t][d];
    len = ol;
  }
  // conv2: K=2, stride=1, pad=0 : len 2 -> 1
  for (int d = 0; d < 30; ++d) coefO[d] = cur[0][d] * c2w[0] + cur[1][d] * c2w[1];
  coefO[29] += c2b[0];
}

// ---------------------------------------------------------------------------
// Kernel 2: mats[b,i,j] = c0 + sum_d coef[d]*obs[b,i,j,d]
// ---------------------------------------------------------------------------
__global__ __launch_bounds__(256) void ssvd_mats_kernel(const float* __restrict__ obs,
                                                        const float* __restrict__ coef,
                                                        float* __restrict__ mats) {
  int idx = blockIdx.x * 256 + threadIdx.x;           // 0 .. 256*128*128-1
  const float* o = obs + (size_t)idx * 29;
  float acc = coef[29];
#pragma unroll
  for (int d = 0; d < 29; ++d) acc += coef[d] * o[d];
  mats[idx] = acc;
}

// ---------------------------------------------------------------------------
// Householder QR sign extraction (LAPACK slarfg convention) on a 128 x ncols
// column-major (stride SA) LDS matrix. Destroys M. dsgn[j] = sign(R_jj).
// ---------------------------------------------------------------------------
__device__ __forceinline__ void householder_signs(float* M, int ncols, float* dsgn,
                                                  double* red, int tid, int lane, int wid) {
  for (int j = 0; j < ncols; ++j) {
    // ||x||^2 over rows j..127 of column j
    double part = 0.0;
    if (tid < 128 && tid >= j) { float x = M[j * SA + tid]; part = (double)x * x; }
    for (int off = 1; off < 64; off <<= 1) part += __shfl_xor(part, off);
    if (lane == 0) red[wid] = part;
    __syncthreads();
    double tot = 0.0;
    for (int w = 0; w < 16; ++w) tot += red[w];
    float alpha = M[j * SA + j];
    double nrm = sqrt(tot);
    double beta = (alpha >= 0.f) ? -nrm : nrm;    // beta = -sign(alpha)*norm
    if (tid == 0) dsgn[j] = (beta >= 0.0) ? 1.f : -1.f;
    double vj = (double)alpha - beta;             // v = x - beta*e_j, v[j]=vj
    double vtv = tot - 2.0 * beta * (double)alpha + beta * beta;
    __syncthreads();
    // apply H = I - 2 v v^T / vtv to columns l > j (one wave per column)
    for (int l = j + 1 + wid; l < ncols; l += 16) {
      double dl = 0.0;
      for (int r = lane; r < 128; r += 64) {
        if (r >= j) {
          double vr = (r == j) ? vj : (double)M[j * SA + r];
          dl += vr * (double)M[l * SA + r];
        }
      }
      for (int off = 1; off < 64; off <<= 1) dl += __shfl_xor(dl, off);
      double f = 2.0 * dl / vtv;
      for (int r = lane; r < 128; r += 64) {
        if (r >= j) {
          double vr = (r == j) ? vj : (double)M[j * SA + r];
          M[l * SA + r] = (float)((double)M[l * SA + r] - f * vr);
        }
      }
    }
    __syncthreads();
  }
}

// ---------------------------------------------------------------------------
// Kernel 3: one-sided Jacobi SVD per 128x128 matrix + sort + QR signs.
// Outputs: Us (128x32, canonical signs), sigma (32), Vs (128x96, canonical).
// ---------------------------------------------------------------------------
__global__ __launch_bounds__(1024) void ssvd_svd_kernel(const float* __restrict__ mats,
                                                        float* __restrict__ UsG,
                                                        float* __restrict__ sigG,
                                                        float* __restrict__ VsG) {
  __shared__ float A[SA * 128];     // working matrix, column-major padded
  __shared__ float V[SA * 128];     // accumulated right rotations
  __shared__ float W[SA * 32];      // Uk copy for QR-U
  __shared__ double sig[128];
  __shared__ double red[16];
  __shared__ int   perm[128];
  __shared__ float sigs[128];
  __shared__ float dsgn[96];

  const int b = blockIdx.x;
  const int tid = threadIdx.x;
  const int lane = tid & 63;
  const int wid = tid >> 6;          // 16 waves
  const float* m = mats + (size_t)b * 16384;

  for (int idx = tid; idx < 16384; idx += 1024) {
    int r = idx >> 7, c = idx & 127;
    A[c * SA + r] = m[idx];
    V[c * SA + r] = (r == c) ? 1.f : 0.f;
  }
  __syncthreads();

  // ---- Jacobi sweeps (round-robin tournament; 64 disjoint pairs/round) ----
  for (int sweep = 0; sweep < NSWEEP; ++sweep) {
    for (int rr = 0; rr < 127; ++rr) {
      for (int pi = wid; pi < 64; pi += 16) {
        int p, q;
        if (pi == 0) { p = 127; q = rr; }
        else { p = (rr + pi) % 127; q = (rr + 127 - pi) % 127; }
        float ap0 = A[p * SA + lane],      ap1 = A[p * SA + 64 + lane];
        float aq0 = A[q * SA + lane],      aq1 = A[q * SA + 64 + lane];
        double al = (double)ap0 * aq0 + (double)ap1 * aq1;
        double be = (double)ap0 * ap0 + (double)ap1 * ap1;
        double ga = (double)aq0 * aq0 + (double)aq1 * aq1;
        for (int off = 1; off < 64; off <<= 1) {
          al += __shfl_xor(al, off);
          be += __shfl_xor(be, off);
          ga += __shfl_xor(ga, off);
        }
        if (al * al > 1e-14 * be * ga) {
          double zeta = (ga - be) / (2.0 * al);
          double t = copysign(1.0, zeta) / (fabs(zeta) + sqrt(1.0 + zeta * zeta));
          double c = 1.0 / sqrt(1.0 + t * t);
          double s = c * t;
          A[p * SA + lane]      = (float)(c * ap0 - s * aq0);
          A[p * SA + 64 + lane] = (float)(c * ap1 - s * aq1);
          A[q * SA + lane]      = (float)(s * ap0 + c * aq0);
          A[q * SA + 64 + lane] = (float)(s * ap1 + c * aq1);
          float vp0 = V[p * SA + lane],      vp1 = V[p * SA + 64 + lane];
          float vq0 = V[q * SA + lane],      vq1 = V[q * SA + 64 + lane];
          V[p * SA + lane]      = (float)(c * vp0 - s * vq0);
          V[p * SA + 64 + lane] = (float)(c * vp1 - s * vq1);
          V[q * SA + lane]      = (float)(s * vp0 + c * vq0);
          V[q * SA + 64 + lane] = (float)(s * vp1 + c * vq1);
        }
      }
      __syncthreads();
    }
  }

  // ---- column norms (sigma) ----
  {
    int j = tid >> 3, sub = tid & 7;
    double ss = 0.0;
    for (int r = sub; r < 128; r += 8) { float x = A[j * SA + r]; ss += (double)x * x; }
    for (int off = 1; off < 8; off <<= 1) ss += __shfl_xor(ss, off);
    if (sub == 0) sig[j] = sqrt(ss);
  }
  __syncthreads();

  // ---- rank-sort descending ----
  if (tid < 128) {
    double sj = sig[tid];
    int rk = 0;
    for (int i = 0; i < 128; ++i) {
      double si = sig[i];
      if (si > sj || (si == sj && i < tid)) ++rk;
    }
    perm[rk] = tid;
    sigs[rk] = (float)sj;
  }
  __syncthreads();

  // ---- W = Uk (top-32 normalized columns) ----
  for (int idx = tid; idx < 128 * 32; idx += 1024) {
    int t = idx >> 7, r = idx & 127;
    W[t * SA + r] = A[perm[t] * SA + r] / sigs[t];
  }
  __syncthreads();

  householder_signs(W, 32, dsgn, red, tid, lane, wid);

  // Us = Uk * D   (A still intact)
  for (int idx = tid; idx < 4096; idx += 1024) {
    int r = idx >> 5, t = idx & 31;
    UsG[((size_t)b * 128 + r) * 32 + t] = dsgn[t] * A[perm[t] * SA + r] / sigs[t];
  }
  if (tid < 32) sigG[b * 32 + tid] = sigs[tid];
  __syncthreads();

  // ---- M = Vr^T (bottom-96 right singular vectors as columns), reuse A ----
  for (int idx = tid; idx < 128 * 96; idx += 1024) {
    int t = idx >> 7, r = idx & 127;
    A[t * SA + r] = V[perm[32 + t] * SA + r];
  }
  __syncthreads();

  householder_signs(A, 96, dsgn, red, tid, lane, wid);

  // Vs = Vr^T * D  (V still intact)
  for (int idx = tid; idx < 12288; idx += 1024) {
    int r = idx / 96, s = idx % 96;
    VsG[((size_t)b * 128 + r) * 96 + s] = dsgn[s] * V[perm[32 + s] * SA + r];
  }
}

// ---------------------------------------------------------------------------
// Kernel 4: per-matrix relu network -> G[b] = (r @ Vs) flattened (128*96)
// ---------------------------------------------------------------------------
__global__ __launch_bounds__(256) void ssvd_net_kernel(const float* __restrict__ UsG,
                                                       const float* __restrict__ sigG,
                                                       const float* __restrict__ VsG,
                                                       const float* __restrict__ w1g,
                                                       const float* __restrict__ w2g,
                                                       float* __restrict__ Gout) {
  __shared__ float R0[128 * 33];
  __shared__ float R1[128 * 33];
  __shared__ float w1s[3][32 * 33];
  __shared__ float w2s[32 * 129];
  __shared__ float vss[128 * 97];
  __shared__ float chnk[128 * 33];
  __shared__ float sgs[32];

  const int b = blockIdx.x, tid = threadIdx.x;

  for (int idx = tid; idx < 4096; idx += 256) {
    int r = idx >> 5, c = idx & 31;
    R0[r * 33 + c] = UsG[((size_t)b * 128 + r) * 32 + c];
  }
  for (int idx = tid; idx < 3072; idx += 256) {
    int i = idx >> 10, rem = idx & 1023, s = rem >> 5, c = rem & 31;
    w1s[i][s * 33 + c] = w1g[idx];
  }
  for (int idx = tid; idx < 4096; idx += 256) {   // weights2[1] only
    int s = idx >> 7, c = idx & 127;
    w2s[s * 129 + c] = w2g[32 * 128 + idx];
  }
  for (int idx = tid; idx < 12288; idx += 256) {
    int r = idx / 96, c = idx % 96;
    vss[r * 97 + c] = VsG[(size_t)b * 12288 + idx];
  }
  if (tid < 32) sgs[tid] = sigG[b * 32 + tid];
  __syncthreads();

  float* cur = R0; float* nxt = R1;
  const int r = tid & 127, hh = tid >> 7;   // hh in {0,1}
  for (int layer = 0; layer < 3; ++layer) {
    const float* wl = w1s[layer];
    float acc[16];
#pragma unroll
    for (int u = 0; u < 16; ++u) acc[u] = 0.f;
    for (int s2 = 0; s2 < 32; ++s2) {
      float rv = cur[r * 33 + s2];
#pragma unroll
      for (int u = 0; u < 16; ++u) acc[u] += rv * wl[s2 * 33 + hh * 16 + u];
    }
#pragma unroll
    for (int u = 0; u < 16; ++u) {
      float v2 = fmaxf(acc[u], 0.f);
      if (layer == 2) v2 = fmaxf(v2 * sgs[hh * 16 + u], 0.f);   // r @ Sigma, relu
      nxt[r * 33 + hh * 16 + u] = v2;
    }
    __syncthreads();
    float* tmp = cur; cur = nxt; nxt = tmp;
  }

  // r4 = relu(cur @ w2[1]) in 32-col chunks; G += relu4 @ Vs
  const int i = tid & 127, h = tid >> 7;
  float gacc[48];
#pragma unroll
  for (int u = 0; u < 48; ++u) gacc[u] = 0.f;
  for (int cc = 0; cc < 4; ++cc) {
    {
      float acc[16];
#pragma unroll
      for (int u = 0; u < 16; ++u) acc[u] = 0.f;
      for (int s2 = 0; s2 < 32; ++s2) {
        float rv = cur[r * 33 + s2];
#pragma unroll
        for (int u = 0; u < 16; ++u) acc[u] += rv * w2s[s2 * 129 + cc * 32 + hh * 16 + u];
      }
#pragma unroll
      for (int u = 0; u < 16; ++u) chnk[r * 33 + hh * 16 + u] = fmaxf(acc[u], 0.f);
    }
    __syncthreads();
    for (int u = 0; u < 32; ++u) {
      float val = chnk[i * 33 + u];
      int vr = cc * 32 + u;
#pragma unroll
      for (int j2 = 0; j2 < 48; ++j2) gacc[j2] += val * vss[vr * 97 + h * 48 + j2];
    }
    __syncthreads();
  }
#pragma unroll
  for (int j2 = 0; j2 < 48; ++j2)
    Gout[(size_t)b * 12288 + i * 96 + h * 48 + j2] = gacc[j2];
}

// ---------------------------------------------------------------------------
// Kernel 5: out(256x256) = G(256x12288) @ weightsO^T(12288x256)
// ---------------------------------------------------------------------------
__global__ __launch_bounds__(256) void ssvd_out_kernel(const float* __restrict__ G,
                                                       const float* __restrict__ wO,
                                                       float* __restrict__ out) {
  __shared__ float Gt[32 * 33];
  __shared__ float Wt[32 * 33];
  const int bi = blockIdx.y, bj = blockIdx.x, tid = threadIdx.x;
  const int tx = tid & 31, ty = tid >> 5;   // ty 0..7
  float acc[4] = {0.f, 0.f, 0.f, 0.f};
  for (int kc = 0; kc < 12288; kc += 32) {
    for (int idx = tid; idx < 1024; idx += 256) {
      int rr = idx >> 5, c = idx & 31;
      Gt[rr * 33 + c] = G[(size_t)(bi * 32 + rr) * 12288 + kc + c];
      Wt[rr * 33 + c] = wO[(size_t)(bj * 32 + rr) * 12288 + kc + c];
    }
    __syncthreads();
    for (int kk = 0; kk < 32; ++kk) {
      float wv = Wt[tx * 33 + kk];
#pragma unroll
      for (int m2 = 0; m2 < 4; ++m2) acc[m2] += Gt[(ty + 8 * m2) * 33 + kk] * wv;
    }
    __syncthreads();
  }
#pragma unroll
  for (int m2 = 0; m2 < 4; ++m2)
    out[(size_t)(bi * 32 + ty + 8 * m2) * 256 + bj * 32 + tx] = acc[m2];
}

// ---------------------------------------------------------------------------
extern "C" void kernel_launch(void* const* d_in, const int* in_sizes, int n_in,
                              void* d_out, int out_size, void* d_ws, size_t ws_size,
                              hipStream_t stream) {
  const float* obs = (const float*)d_in[0];
  const float* w1  = (const float*)d_in[1];
  const float* w2  = (const float*)d_in[2];
  const float* wO  = (const float*)d_in[3];
  const float* c1w = (const float*)d_in[4];
  const float* c1b = (const float*)d_in[5];
  const float* c2w = (const float*)d_in[6];
  const float* c2b = (const float*)d_in[7];
  float* out = (float*)d_out;

  char* ws = (char*)d_ws;
  float* coef = (float*)(ws);                                   //   128 B (30 used)
  float* Us   = (float*)(ws + 1024);                            //  4.19 MB
  float* sg   = (float*)(ws + 1024 + 4194304);                  //   32 KB
  float* Vs   = (float*)(ws + 1024 + 4194304 + 32768);          // 12.58 MB
  float* mats = (float*)(ws + 1024 + 4194304 + 32768 + 12582912); // 16.78 MB
  float* G = mats;  // alias: mats consumed by SVD before net writes G

  ssvd_coef_kernel<<<1, 64, 0, stream>>>(c1w, c1b, c2w, c2b, coef);
  ssvd_mats_kernel<<<16384, 256, 0, stream>>>(obs, coef, mats);
  ssvd_svd_kernel<<<256, 1024, 0, stream>>>(mats, Us, sg, Vs);
  ssvd_net_kernel<<<256, 256, 0, stream>>>(Us, sg, Vs, w1, w2, G);
  ssvd_out_kernel<<<dim3(8, 8), 256, 0, stream>>>(G, wO, out);
}

// Round 2
// 4649.495 us; speedup vs baseline: 3.2960x; 3.2960x over previous
//
#include <hip/hip_runtime.h>
#include <math.h>

#define NSWEEP 12
#define SA 132   // padded LDS column stride (floats); 132*4=528B = 16B-aligned columns

// ---------------------------------------------------------------------------
// Kernel 1: collapse feature-weighting + conv chain into affine coef[29], c0.
// ---------------------------------------------------------------------------
__global__ void ssvd_coef_kernel(const float* __restrict__ c1w, const float* __restrict__ c1b,
                                 const float* __restrict__ c2w, const float* __restrict__ c2b,
                                 float* __restrict__ coefO) {
  if (threadIdx.x != 0 || blockIdx.x != 0) return;
  float cur[6][30], nxt[6][30];
  for (int i = 0; i < 6; ++i)
    for (int d = 0; d < 30; ++d) { cur[i][d] = 0.f; nxt[i][d] = 0.f; }
  const int FS[6] = {5, 5, 3, 8, 6, 2};
  int p = 0;
  for (int f = 0; f < 6; ++f) {
    for (int j = 0; j < FS[f]; ++j) cur[f][p + j] = (float)j;
    p += FS[f];
  }
  int len = 6;
  for (int rep = 0; rep < 3; ++rep) {       // conv1 x3: K=4, stride=2, pad=2
    int ol = len / 2 + 1;
    for (int t = 0; t < ol; ++t) {
      for (int d = 0; d < 30; ++d) {
        float acc = 0.f;
        for (int kk = 0; kk < 4; ++kk) {
          int ix = 2 * t - 2 + kk;
          if (ix >= 0 && ix < len) acc += cur[ix][d] * c1w[kk];
        }
        nxt[t][d] = acc;
      }
      nxt[t][29] += c1b[0];
    }
    for (int t = 0; t < ol; ++t)
      for (int d = 0; d < 30; ++d) cur[t][d] = nxt[t][d];
    len = ol;
  }
  // conv2: K=2, stride=1, pad=0 : len 2 -> 1
  for (int d = 0; d < 30; ++d) coefO[d] = cur[0][d] * c2w[0] + cur[1][d] * c2w[1];
  coefO[29] += c2b[0];
}

// ---------------------------------------------------------------------------
// Kernel 2: mats[b,i,j] = c0 + sum_d coef[d]*obs[b,i,j,d]
// ---------------------------------------------------------------------------
__global__ __launch_bounds__(256) void ssvd_mats_kernel(const float* __restrict__ obs,
                                                        const float* __restrict__ coef,
                                                        float* __restrict__ mats) {
  int idx = blockIdx.x * 256 + threadIdx.x;           // 0 .. 256*128*128-1
  const float* o = obs + (size_t)idx * 29;
  float acc = coef[29];
#pragma unroll
  for (int d = 0; d < 29; ++d) acc += coef[d] * o[d];
  mats[idx] = acc;
}

__device__ __forceinline__ float f4dot(float4 a, float4 b) {
  return a.x * b.x + a.y * b.y + a.z * b.z + a.w * b.w;
}
__device__ __forceinline__ float4 f4rot(float c, float s, float4 a, float4 b) {
  // c*a - s*b
  float4 r;
  r.x = c * a.x - s * b.x; r.y = c * a.y - s * b.y;
  r.z = c * a.z - s * b.z; r.w = c * a.w - s * b.w;
  return r;
}

// ---------------------------------------------------------------------------
// Householder QR sign extraction (LAPACK slarfg convention) on a 128 x ncols
// column-major (stride SA) LDS matrix. Destroys M. dsgn[j] = sign(R_jj).
// ---------------------------------------------------------------------------
__device__ __forceinline__ void householder_signs(float* M, int ncols, float* dsgn,
                                                  double* red, int tid, int lane, int wid) {
  for (int j = 0; j < ncols; ++j) {
    // ||x||^2 over rows j..127 of column j
    double part = 0.0;
    if (tid < 128 && tid >= j) { float x = M[j * SA + tid]; part = (double)x * x; }
    for (int off = 1; off < 64; off <<= 1) part += __shfl_xor(part, off);
    if (lane == 0) red[wid] = part;
    __syncthreads();
    double tot = 0.0;
    for (int w = 0; w < 16; ++w) tot += red[w];
    float alpha = M[j * SA + j];
    double nrm = sqrt(tot);
    double beta = (alpha >= 0.f) ? -nrm : nrm;    // beta = -sign(alpha)*norm
    if (tid == 0) dsgn[j] = (beta >= 0.0) ? 1.f : -1.f;
    double vj = (double)alpha - beta;             // v = x - beta*e_j, v[j]=vj
    double vtv = tot - 2.0 * beta * (double)alpha + beta * beta;
    __syncthreads();
    // apply H = I - 2 v v^T / vtv to columns l > j (one wave per column)
    for (int l = j + 1 + wid; l < ncols; l += 16) {
      double dl = 0.0;
      for (int r = lane; r < 128; r += 64) {
        if (r >= j) {
          double vr = (r == j) ? vj : (double)M[j * SA + r];
          dl += vr * (double)M[l * SA + r];
        }
      }
      for (int off = 1; off < 64; off <<= 1) dl += __shfl_xor(dl, off);
      double f = 2.0 * dl / vtv;
      for (int r = lane; r < 128; r += 64) {
        if (r >= j) {
          double vr = (r == j) ? vj : (double)M[j * SA + r];
          M[l * SA + r] = (float)((double)M[l * SA + r] - f * vr);
        }
      }
    }
    __syncthreads();
  }
}

// ---------------------------------------------------------------------------
// Kernel 3: one-sided Jacobi SVD per 128x128 matrix + sort + QR signs.
// 64 pairs run concurrently: 16 threads/pair, 8 rows/thread, fp32 rotations,
// cached column norms (only alpha = p.q needs a dot), b128 LDS traffic.
// Outputs: Us (128x32, canonical signs), sigma (32), Vs (128x96, canonical).
// ---------------------------------------------------------------------------
__global__ __launch_bounds__(1024) void ssvd_svd_kernel(const float* __restrict__ mats,
                                                        float* __restrict__ UsG,
                                                        float* __restrict__ sigG,
                                                        float* __restrict__ VsG) {
  __shared__ __align__(16) float A[SA * 128];   // working matrix, column-major padded
  __shared__ __align__(16) float V[SA * 128];   // accumulated right rotations
  __shared__ __align__(16) float W[SA * 32];    // Uk copy for QR-U
  __shared__ float nrmS[128];                   // cached squared column norms
  __shared__ double sig[128];
  __shared__ double red[16];
  __shared__ int   perm[128];
  __shared__ float sigs[128];
  __shared__ float dsgn[96];

  const int b = blockIdx.x;
  const int tid = threadIdx.x;
  const int lane = tid & 63;
  const int wid = tid >> 6;          // 16 waves
  const int grp = tid >> 4;          // 0..63 : pair index
  const int sub = tid & 15;          // 0..15 within pair-group
  const int rbase = 4 * sub;         // rows rbase..rbase+3 and 64+rbase..
  const float* m = mats + (size_t)b * 16384;

  for (int idx = tid; idx < 16384; idx += 1024) {
    int r = idx >> 7, c = idx & 127;
    A[c * SA + r] = m[idx];
    V[c * SA + r] = (r == c) ? 1.f : 0.f;
  }
  __syncthreads();

  // initial squared column norms (double accum, stored fp32)
  {
    int j = tid >> 3, s8 = tid & 7;
    double ss = 0.0;
    for (int r = s8; r < 128; r += 8) { float x = A[j * SA + r]; ss += (double)x * x; }
    for (int off = 1; off < 8; off <<= 1) ss += __shfl_xor(ss, off);
    if (s8 == 0) nrmS[j] = (float)ss;
  }
  __syncthreads();

  // ---- Jacobi sweeps (round-robin tournament; 64 concurrent pairs/round) ----
  for (int sweep = 0; sweep < NSWEEP; ++sweep) {
    int rotcnt = 0;
    for (int rr = 0; rr < 127; ++rr) {
      int p, q;
      if (grp == 0) { p = 127; q = rr; }
      else { p = (rr + grp) % 127; q = (rr + 127 - grp) % 127; }
      float* Ap = &A[p * SA]; float* Aq = &A[q * SA];
      float4 ap0 = *(const float4*)(Ap + rbase);
      float4 ap1 = *(const float4*)(Ap + 64 + rbase);
      float4 aq0 = *(const float4*)(Aq + rbase);
      float4 aq1 = *(const float4*)(Aq + 64 + rbase);
      float al = f4dot(ap0, aq0) + f4dot(ap1, aq1);
      al += __shfl_xor(al, 1); al += __shfl_xor(al, 2);
      al += __shfl_xor(al, 4); al += __shfl_xor(al, 8);
      float be = nrmS[p], ga = nrmS[q];
      bool apply = ((double)al * al > 1e-12 * (double)be * (double)ga);
      if (apply) {
        double zeta = ((double)ga - (double)be) / (2.0 * (double)al);
        double t = copysign(1.0, zeta) / (fabs(zeta) + sqrt(1.0 + zeta * zeta));
        double cd = 1.0 / sqrt(1.0 + t * t);
        float c = (float)cd, s = (float)(cd * t);
        *(float4*)(Ap + rbase)      = f4rot(c, s, ap0, aq0);
        *(float4*)(Ap + 64 + rbase) = f4rot(c, s, ap1, aq1);
        *(float4*)(Aq + rbase)      = f4rot(c, -s, aq0, ap0);   // s*ap + c*aq
        *(float4*)(Aq + 64 + rbase) = f4rot(c, -s, aq1, ap1);
        float* Vp = &V[p * SA]; float* Vq = &V[q * SA];
        float4 vp0 = *(const float4*)(Vp + rbase);
        float4 vp1 = *(const float4*)(Vp + 64 + rbase);
        float4 vq0 = *(const float4*)(Vq + rbase);
        float4 vq1 = *(const float4*)(Vq + 64 + rbase);
        *(float4*)(Vp + rbase)      = f4rot(c, s, vp0, vq0);
        *(float4*)(Vp + 64 + rbase) = f4rot(c, s, vp1, vq1);
        *(float4*)(Vq + rbase)      = f4rot(c, -s, vq0, vp0);
        *(float4*)(Vq + 64 + rbase) = f4rot(c, -s, vq1, vp1);
        if (sub == 0) {
          double cs = (double)c * (double)s, c2 = (double)c * c, s2 = (double)s * s;
          nrmS[p] = (float)(c2 * be - 2.0 * cs * al + s2 * ga);
          nrmS[q] = (float)(s2 * be + 2.0 * cs * al + c2 * ga);
        }
      }
      rotcnt += __syncthreads_count(apply && sub == 0);
    }
    if (rotcnt == 0) break;
  }

  // ---- column norms (sigma), fresh double recompute ----
  {
    int j = tid >> 3, s8 = tid & 7;
    double ss = 0.0;
    for (int r = s8; r < 128; r += 8) { float x = A[j * SA + r]; ss += (double)x * x; }
    for (int off = 1; off < 8; off <<= 1) ss += __shfl_xor(ss, off);
    if (s8 == 0) sig[j] = sqrt(ss);
  }
  __syncthreads();

  // ---- rank-sort descending ----
  if (tid < 128) {
    double sj = sig[tid];
    int rk = 0;
    for (int i = 0; i < 128; ++i) {
      double si = sig[i];
      if (si > sj || (si == sj && i < tid)) ++rk;
    }
    perm[rk] = tid;
    sigs[rk] = (float)sj;
  }
  __syncthreads();

  // ---- W = Uk (top-32 normalized columns) ----
  for (int idx = tid; idx < 128 * 32; idx += 1024) {
    int t = idx >> 7, r = idx & 127;
    W[t * SA + r] = A[perm[t] * SA + r] / sigs[t];
  }
  __syncthreads();

  householder_signs(W, 32, dsgn, red, tid, lane, wid);

  // Us = Uk * D   (A still intact)
  for (int idx = tid; idx < 4096; idx += 1024) {
    int r = idx >> 5, t = idx & 31;
    UsG[((size_t)b * 128 + r) * 32 + t] = dsgn[t] * A[perm[t] * SA + r] / sigs[t];
  }
  if (tid < 32) sigG[b * 32 + tid] = sigs[tid];
  __syncthreads();

  // ---- M = Vr^T (bottom-96 right singular vectors as columns), reuse A ----
  for (int idx = tid; idx < 128 * 96; idx += 1024) {
    int t = idx >> 7, r = idx & 127;
    A[t * SA + r] = V[perm[32 + t] * SA + r];
  }
  __syncthreads();

  householder_signs(A, 96, dsgn, red, tid, lane, wid);

  // Vs = Vr^T * D  (V still intact)
  for (int idx = tid; idx < 12288; idx += 1024) {
    int r = idx / 96, s = idx % 96;
    VsG[((size_t)b * 128 + r) * 96 + s] = dsgn[s] * V[perm[32 + s] * SA + r];
  }
}

// ---------------------------------------------------------------------------
// Kernel 4: per-matrix relu network -> G[b] = (r @ Vs) flattened (128*96)
// ---------------------------------------------------------------------------
__global__ __launch_bounds__(256) void ssvd_net_kernel(const float* __restrict__ UsG,
                                                       const float* __restrict__ sigG,
                                                       const float* __restrict__ VsG,
                                                       const float* __restrict__ w1g,
                                                       const float* __restrict__ w2g,
                                                       float* __restrict__ Gout) {
  __shared__ float R0[128 * 33];
  __shared__ float R1[128 * 33];
  __shared__ float w1s[3][32 * 33];
  __shared__ float w2s[32 * 129];
  __shared__ float vss[128 * 97];
  __shared__ float chnk[128 * 33];
  __shared__ float sgs[32];

  const int b = blockIdx.x, tid = threadIdx.x;

  for (int idx = tid; idx < 4096; idx += 256) {
    int r = idx >> 5, c = idx & 31;
    R0[r * 33 + c] = UsG[((size_t)b * 128 + r) * 32 + c];
  }
  for (int idx = tid; idx < 3072; idx += 256) {
    int i = idx >> 10, rem = idx & 1023, s = rem >> 5, c = rem & 31;
    w1s[i][s * 33 + c] = w1g[idx];
  }
  for (int idx = tid; idx < 4096; idx += 256) {   // weights2[1] only
    int s = idx >> 7, c = idx & 127;
    w2s[s * 129 + c] = w2g[32 * 128 + idx];
  }
  for (int idx = tid; idx < 12288; idx += 256) {
    int r = idx / 96, c = idx % 96;
    vss[r * 97 + c] = VsG[(size_t)b * 12288 + idx];
  }
  if (tid < 32) sgs[tid] = sigG[b * 32 + tid];
  __syncthreads();

  float* cur = R0; float* nxt = R1;
  const int r = tid & 127, hh = tid >> 7;   // hh in {0,1}
  for (int layer = 0; layer < 3; ++layer) {
    const float* wl = w1s[layer];
    float acc[16];
#pragma unroll
    for (int u = 0; u < 16; ++u) acc[u] = 0.f;
    for (int s2 = 0; s2 < 32; ++s2) {
      float rv = cur[r * 33 + s2];
#pragma unroll
      for (int u = 0; u < 16; ++u) acc[u] += rv * wl[s2 * 33 + hh * 16 + u];
    }
#pragma unroll
    for (int u = 0; u < 16; ++u) {
      float v2 = fmaxf(acc[u], 0.f);
      if (layer == 2) v2 = fmaxf(v2 * sgs[hh * 16 + u], 0.f);   // r @ Sigma, relu
      nxt[r * 33 + hh * 16 + u] = v2;
    }
    __syncthreads();
    float* tmp = cur; cur = nxt; nxt = tmp;
  }

  // r4 = relu(cur @ w2[1]) in 32-col chunks; G += relu4 @ Vs
  const int i = tid & 127, h = tid >> 7;
  float gacc[48];
#pragma unroll
  for (int u = 0; u < 48; ++u) gacc[u] = 0.f;
  for (int cc = 0; cc < 4; ++cc) {
    {
      float acc[16];
#pragma unroll
      for (int u = 0; u < 16; ++u) acc[u] = 0.f;
      for (int s2 = 0; s2 < 32; ++s2) {
        float rv = cur[r * 33 + s2];
#pragma unroll
        for (int u = 0; u < 16; ++u) acc[u] += rv * w2s[s2 * 129 + cc * 32 + hh * 16 + u];
      }
#pragma unroll
      for (int u = 0; u < 16; ++u) chnk[r * 33 + hh * 16 + u] = fmaxf(acc[u], 0.f);
    }
    __syncthreads();
    for (int u = 0; u < 32; ++u) {
      float val = chnk[i * 33 + u];
      int vr = cc * 32 + u;
#pragma unroll
      for (int j2 = 0; j2 < 48; ++j2) gacc[j2] += val * vss[vr * 97 + h * 48 + j2];
    }
    __syncthreads();
  }
#pragma unroll
  for (int j2 = 0; j2 < 48; ++j2)
    Gout[(size_t)b * 12288 + i * 96 + h * 48 + j2] = gacc[j2];
}

// ---------------------------------------------------------------------------
// Kernel 5: out(256x256) = G(256x12288) @ weightsO^T(12288x256)
// ---------------------------------------------------------------------------
__global__ __launch_bounds__(256) void ssvd_out_kernel(const float* __restrict__ G,
                                                       const float* __restrict__ wO,
                                                       float* __restrict__ out) {
  __shared__ float Gt[32 * 33];
  __shared__ float Wt[32 * 33];
  const int bi = blockIdx.y, bj = blockIdx.x, tid = threadIdx.x;
  const int tx = tid & 31, ty = tid >> 5;   // ty 0..7
  float acc[4] = {0.f, 0.f, 0.f, 0.f};
  for (int kc = 0; kc < 12288; kc += 32) {
    for (int idx = tid; idx < 1024; idx += 256) {
      int rr = idx >> 5, c = idx & 31;
      Gt[rr * 33 + c] = G[(size_t)(bi * 32 + rr) * 12288 + kc + c];
      Wt[rr * 33 + c] = wO[(size_t)(bj * 32 + rr) * 12288 + kc + c];
    }
    __syncthreads();
    for (int kk = 0; kk < 32; ++kk) {
      float wv = Wt[tx * 33 + kk];
#pragma unroll
      for (int m2 = 0; m2 < 4; ++m2) acc[m2] += Gt[(ty + 8 * m2) * 33 + kk] * wv;
    }
    __syncthreads();
  }
#pragma unroll
  for (int m2 = 0; m2 < 4; ++m2)
    out[(size_t)(bi * 32 + ty + 8 * m2) * 256 + bj * 32 + tx] = acc[m2];
}

// ---------------------------------------------------------------------------
extern "C" void kernel_launch(void* const* d_in, const int* in_sizes, int n_in,
                              void* d_out, int out_size, void* d_ws, size_t ws_size,
                              hipStream_t stream) {
  const float* obs = (const float*)d_in[0];
  const float* w1  = (const float*)d_in[1];
  const float* w2  = (const float*)d_in[2];
  const float* wO  = (const float*)d_in[3];
  const float* c1w = (const float*)d_in[4];
  const float* c1b = (const float*)d_in[5];
  const float* c2w = (const float*)d_in[6];
  const float* c2b = (const float*)d_in[7];
  float* out = (float*)d_out;

  char* ws = (char*)d_ws;
  float* coef = (float*)(ws);                                   //   128 B (30 used)
  float* Us   = (float*)(ws + 1024);                            //  4.19 MB
  float* sg   = (float*)(ws + 1024 + 4194304);                  //   32 KB
  float* Vs   = (float*)(ws + 1024 + 4194304 + 32768);          // 12.58 MB
  float* mats = (float*)(ws + 1024 + 4194304 + 32768 + 12582912); // 16.78 MB
  float* G = mats;  // alias: mats consumed by SVD before net writes G

  ssvd_coef_kernel<<<1, 64, 0, stream>>>(c1w, c1b, c2w, c2b, coef);
  ssvd_mats_kernel<<<16384, 256, 0, stream>>>(obs, coef, mats);
  ssvd_svd_kernel<<<256, 1024, 0, stream>>>(mats, Us, sg, Vs);
  ssvd_net_kernel<<<256, 256, 0, stream>>>(Us, sg, Vs, w1, w2, G);
  ssvd_out_kernel<<<dim3(8, 8), 256, 0, stream>>>(G, wO, out);
}

// Round 3
// 3726.928 us; speedup vs baseline: 4.1119x; 1.2475x over previous
//
#include <hip/hip_runtime.h>
#include <math.h>

#define NSWEEP 16
#define SA 132   // padded LDS column stride (floats); 132*4=528B, 16B-aligned columns

// ---------------------------------------------------------------------------
// Kernel 1: collapse feature-weighting + conv chain into affine coef[29], c0.
// ---------------------------------------------------------------------------
__global__ void ssvd_coef_kernel(const float* __restrict__ c1w, const float* __restrict__ c1b,
                                 const float* __restrict__ c2w, const float* __restrict__ c2b,
                                 float* __restrict__ coefO) {
  if (threadIdx.x != 0 || blockIdx.x != 0) return;
  float cur[6][30], nxt[6][30];
  for (int i = 0; i < 6; ++i)
    for (int d = 0; d < 30; ++d) { cur[i][d] = 0.f; nxt[i][d] = 0.f; }
  const int FS[6] = {5, 5, 3, 8, 6, 2};
  int p = 0;
  for (int f = 0; f < 6; ++f) {
    for (int j = 0; j < FS[f]; ++j) cur[f][p + j] = (float)j;
    p += FS[f];
  }
  int len = 6;
  for (int rep = 0; rep < 3; ++rep) {       // conv1 x3: K=4, stride=2, pad=2
    int ol = len / 2 + 1;
    for (int t = 0; t < ol; ++t) {
      for (int d = 0; d < 30; ++d) {
        float acc = 0.f;
        for (int kk = 0; kk < 4; ++kk) {
          int ix = 2 * t - 2 + kk;
          if (ix >= 0 && ix < len) acc += cur[ix][d] * c1w[kk];
        }
        nxt[t][d] = acc;
      }
      nxt[t][29] += c1b[0];
    }
    for (int t = 0; t < ol; ++t)
      for (int d = 0; d < 30; ++d) cur[t][d] = nxt[t][d];
    len = ol;
  }
  // conv2: K=2, stride=1, pad=0 : len 2 -> 1
  for (int d = 0; d < 30; ++d) coefO[d] = cur[0][d] * c2w[0] + cur[1][d] * c2w[1];
  coefO[29] += c2b[0];
}

// ---------------------------------------------------------------------------
// Kernel 2: mats[b,i,j] = c0 + sum_d coef[d]*obs[b,i,j,d]
// Block covers 256 outputs = 7424 floats = 29696 B (16B-divisible): stage via
// coalesced float4 into LDS, then stride-29 LDS reads (29 coprime 32 => 2-way max).
// ---------------------------------------------------------------------------
__global__ __launch_bounds__(256) void ssvd_mats_kernel(const float* __restrict__ obs,
                                                        const float* __restrict__ coef,
                                                        float* __restrict__ mats) {
  __shared__ __align__(16) float tile[7424];
  __shared__ float cf[32];
  const int tid = threadIdx.x;
  const float4* src = (const float4*)(obs + (size_t)blockIdx.x * 7424);
  float4* dst = (float4*)tile;
  for (int i = tid; i < 1856; i += 256) dst[i] = src[i];
  if (tid < 30) cf[tid] = coef[tid];
  __syncthreads();
  const float* row = tile + tid * 29;
  float acc = cf[29];
#pragma unroll
  for (int d = 0; d < 29; ++d) acc += cf[d] * row[d];
  mats[(size_t)blockIdx.x * 256 + tid] = acc;
}

__device__ __forceinline__ float f4dot(float4 a, float4 b) {
  return a.x * b.x + a.y * b.y + a.z * b.z + a.w * b.w;
}
__device__ __forceinline__ float4 f4rot(float c, float s, float4 a, float4 b) {
  // c*a - s*b
  float4 r;
  r.x = c * a.x - s * b.x; r.y = c * a.y - s * b.y;
  r.z = c * a.z - s * b.z; r.w = c * a.w - s * b.w;
  return r;
}

// ---------------------------------------------------------------------------
// Reduction-free Householder sign extraction for a 128 x ncols matrix with
// (near-)orthonormal columns, column-major stride SA. Destroys M.
// Exact-orthonormal case: ||x||=1, v^T a_l = sg*a_l[j] -> no reductions.
// Reflections are exactly orthogonal for any v, so errors stay O(eps).
// dsgn[j] = sign(R_jj) = -sign(alpha_j)  (LAPACK slarfg convention).
// ---------------------------------------------------------------------------
__device__ __forceinline__ void householder_signs_fast(float* M, int ncols, float* dsgn,
                                                       int tid, int lane, int wid) {
  for (int j = 0; j < ncols; ++j) {
    float alpha = M[j * SA + j];
    float sg = (alpha >= 0.f) ? 1.f : -1.f;
    if (tid == 0) dsgn[j] = -sg;
    float inv = 1.f / (1.f + sg * alpha);
    for (int l = j + 1 + wid; l < ncols; l += 16) {
      float fl = -sg * M[l * SA + j] * inv;
      for (int r = lane; r < 128; r += 64) {
        float vr = M[j * SA + r] + ((r == j) ? sg : 0.f);
        M[l * SA + r] += fl * vr;
      }
    }
    __syncthreads();
  }
}

// ---------------------------------------------------------------------------
// Kernel 3: one-sided Jacobi SVD per 128x128 matrix.
// Register-resident columns + XOR-tournament with migrating Y columns:
//   level lev (0..6), rounds k=0..(64>>lev)-1, pair m = ((2k+1)<<lev).
//   Group g statically holds column X (bit lev = 0) in registers for the
//   whole level; partner column Y = X ^ m migrates through its LDS slot
//   (write-if-rotated, barrier, read next). 1 column (A+V) moved per group
//   per round vs 4 read+written in the naive scheme.
// Outputs: Us (128x32, canonical signs), sigma (32), Vs (128x96, canonical).
// ---------------------------------------------------------------------------
__global__ __launch_bounds__(1024) void ssvd_svd_kernel(const float* __restrict__ mats,
                                                        float* __restrict__ UsG,
                                                        float* __restrict__ sigG,
                                                        float* __restrict__ VsG) {
  __shared__ __align__(16) float A[SA * 128];   // column slots (by column id)
  __shared__ __align__(16) float V[SA * 128];
  __shared__ __align__(16) float W[SA * 32];
  __shared__ float nrmS[128];
  __shared__ double sig[128];
  __shared__ int   perm[128];
  __shared__ float sigs[128];
  __shared__ float dsgn[96];
  __shared__ int   rotFlag[NSWEEP];

  const int b = blockIdx.x;
  const int tid = threadIdx.x;
  const int lane = tid & 63;
  const int wid = tid >> 6;          // 16 waves
  const int g = tid >> 4;            // 0..63 : group (pair processor)
  const int s = tid & 15;            // 0..15 within group
  const int rb = 4 * s;              // rows rb..rb+3 and 64+rb..64+rb+3
  const float* mp = mats + (size_t)b * 16384;

  for (int idx = tid; idx < 16384; idx += 1024) {
    int r = idx >> 7, c = idx & 127;
    A[c * SA + r] = mp[idx];
    V[c * SA + r] = (r == c) ? 1.f : 0.f;
  }
  if (tid < NSWEEP) rotFlag[tid] = 0;
  __syncthreads();

  // initial squared column norms
  {
    int j = tid >> 3, s8 = tid & 7;
    double ss = 0.0;
    for (int r = s8; r < 128; r += 8) { float x = A[j * SA + r]; ss += (double)x * x; }
    for (int off = 1; off < 8; off <<= 1) ss += __shfl_xor(ss, off);
    if (s8 == 0) nrmS[j] = (float)ss;
  }
  __syncthreads();

  // ---- Jacobi sweeps: XOR tournament, register-resident columns ----
  for (int sweep = 0; sweep < NSWEEP; ++sweep) {
    for (int lev = 0; lev < 7; ++lev) {
      const int L = 64 >> lev;
      const int xid = ((g >> lev) << (lev + 1)) | (g & ((1 << lev) - 1));  // bit lev = 0
      int yid = xid | (1 << lev);                                          // m_0 = 1<<lev
      float4 xa0 = *(const float4*)&A[xid * SA + rb];
      float4 xa1 = *(const float4*)&A[xid * SA + 64 + rb];
      float4 xv0 = *(const float4*)&V[xid * SA + rb];
      float4 xv1 = *(const float4*)&V[xid * SA + 64 + rb];
      float xn = nrmS[xid];
      float4 ya0 = *(const float4*)&A[yid * SA + rb];
      float4 ya1 = *(const float4*)&A[yid * SA + 64 + rb];
      float4 yv0 = *(const float4*)&V[yid * SA + rb];
      float4 yv1 = *(const float4*)&V[yid * SA + 64 + rb];
      float yn = nrmS[yid];

      for (int k = 0; k < L; ++k) {
        float al = f4dot(xa0, ya0) + f4dot(xa1, ya1);
        al += __shfl_xor(al, 1); al += __shfl_xor(al, 2);
        al += __shfl_xor(al, 4); al += __shfl_xor(al, 8);
        bool apply = (al * al > 1e-12f * xn * yn);
        if (apply) {
          float zeta = (yn - xn) / (2.0f * al);
          float t = copysignf(1.0f, zeta) / (fabsf(zeta) + sqrtf(1.0f + zeta * zeta));
          float cc = 1.0f / sqrtf(1.0f + t * t);
          float sn = cc * t;
          float4 oa0 = xa0, oa1 = xa1, ov0 = xv0, ov1 = xv1;
          xa0 = f4rot(cc, sn, xa0, ya0);  xa1 = f4rot(cc, sn, xa1, ya1);
          ya0 = f4rot(cc, -sn, ya0, oa0); ya1 = f4rot(cc, -sn, ya1, oa1);
          xv0 = f4rot(cc, sn, xv0, yv0);  xv1 = f4rot(cc, sn, xv1, yv1);
          yv0 = f4rot(cc, -sn, yv0, ov0); yv1 = f4rot(cc, -sn, yv1, ov1);
          xn = fmaxf(xn - t * al, 0.f);
          yn = fmaxf(yn + t * al, 0.f);
          if (s == 0) rotFlag[sweep] = 1;
        }
        if (k < L - 1) {
          int nyid = xid ^ ((((k + 1) << 1) | 1) << lev);
          if (apply) {
            *(float4*)&A[yid * SA + rb]      = ya0;
            *(float4*)&A[yid * SA + 64 + rb] = ya1;
            *(float4*)&V[yid * SA + rb]      = yv0;
            *(float4*)&V[yid * SA + 64 + rb] = yv1;
            if (s == 0) nrmS[yid] = yn;
          }
          __syncthreads();
          ya0 = *(const float4*)&A[nyid * SA + rb];
          ya1 = *(const float4*)&A[nyid * SA + 64 + rb];
          yv0 = *(const float4*)&V[nyid * SA + rb];
          yv1 = *(const float4*)&V[nyid * SA + 64 + rb];
          yn = nrmS[nyid];
          yid = nyid;
        }
      }
      // level-end dump of both columns
      *(float4*)&A[xid * SA + rb]      = xa0;
      *(float4*)&A[xid * SA + 64 + rb] = xa1;
      *(float4*)&V[xid * SA + rb]      = xv0;
      *(float4*)&V[xid * SA + 64 + rb] = xv1;
      *(float4*)&A[yid * SA + rb]      = ya0;
      *(float4*)&A[yid * SA + 64 + rb] = ya1;
      *(float4*)&V[yid * SA + rb]      = yv0;
      *(float4*)&V[yid * SA + 64 + rb] = yv1;
      if (s == 0) { nrmS[xid] = xn; nrmS[yid] = yn; }
      __syncthreads();
    }
    if (rotFlag[sweep] == 0) break;   // converged: full sweep verified no rotation
  }

  // ---- column norms (sigma), fresh double recompute ----
  {
    int j = tid >> 3, s8 = tid & 7;
    double ss = 0.0;
    for (int r = s8; r < 128; r += 8) { float x = A[j * SA + r]; ss += (double)x * x; }
    for (int off = 1; off < 8; off <<= 1) ss += __shfl_xor(ss, off);
    if (s8 == 0) sig[j] = sqrt(ss);
  }
  __syncthreads();

  // ---- rank-sort descending ----
  if (tid < 128) {
    double sj = sig[tid];
    int rk = 0;
    for (int i = 0; i < 128; ++i) {
      double si = sig[i];
      if (si > sj || (si == sj && i < tid)) ++rk;
    }
    perm[rk] = tid;
    sigs[rk] = (float)sj;
  }
  __syncthreads();

  // ---- W = Uk (top-32 normalized columns) ----
  for (int idx = tid; idx < 128 * 32; idx += 1024) {
    int t = idx >> 7, r = idx & 127;
    W[t * SA + r] = A[perm[t] * SA + r] / sigs[t];
  }
  __syncthreads();

  householder_signs_fast(W, 32, dsgn, tid, lane, wid);

  // Us = Uk * D   (A still intact)
  for (int idx = tid; idx < 4096; idx += 1024) {
    int r = idx >> 5, t = idx & 31;
    UsG[((size_t)b * 128 + r) * 32 + t] = dsgn[t] * A[perm[t] * SA + r] / sigs[t];
  }
  if (tid < 32) sigG[b * 32 + tid] = sigs[tid];
  __syncthreads();

  // ---- M = Vr^T (bottom-96 right singular vectors as columns), reuse A ----
  for (int idx = tid; idx < 128 * 96; idx += 1024) {
    int t = idx >> 7, r = idx & 127;
    A[t * SA + r] = V[perm[32 + t] * SA + r];
  }
  __syncthreads();

  householder_signs_fast(A, 96, dsgn, tid, lane, wid);

  // Vs = Vr^T * D  (V still intact)
  for (int idx = tid; idx < 12288; idx += 1024) {
    int r = idx / 96, ss2 = idx % 96;
    VsG[((size_t)b * 128 + r) * 96 + ss2] = dsgn[ss2] * V[perm[32 + ss2] * SA + r];
  }
}

// ---------------------------------------------------------------------------
// Kernel 4: per-matrix relu network -> G[b] = (r @ Vs) flattened (128*96)
// ---------------------------------------------------------------------------
__global__ __launch_bounds__(256) void ssvd_net_kernel(const float* __restrict__ UsG,
                                                       const float* __restrict__ sigG,
                                                       const float* __restrict__ VsG,
                                                       const float* __restrict__ w1g,
                                                       const float* __restrict__ w2g,
                                                       float* __restrict__ Gout) {
  __shared__ float R0[128 * 33];
  __shared__ float R1[128 * 33];
  __shared__ float w1s[3][32 * 33];
  __shared__ float w2s[32 * 129];
  __shared__ float vss[128 * 97];
  __shared__ float chnk[128 * 33];
  __shared__ float sgs[32];

  const int b = blockIdx.x, tid = threadIdx.x;

  for (int idx = tid; idx < 4096; idx += 256) {
    int r = idx >> 5, c = idx & 31;
    R0[r * 33 + c] = UsG[((size_t)b * 128 + r) * 32 + c];
  }
  for (int idx = tid; idx < 3072; idx += 256) {
    int i = idx >> 10, rem = idx & 1023, s = rem >> 5, c = rem & 31;
    w1s[i][s * 33 + c] = w1g[idx];
  }
  for (int idx = tid; idx < 4096; idx += 256) {   // weights2[1] only
    int s = idx >> 7, c = idx & 127;
    w2s[s * 129 + c] = w2g[32 * 128 + idx];
  }
  for (int idx = tid; idx < 12288; idx += 256) {
    int r = idx / 96, c = idx % 96;
    vss[r * 97 + c] = VsG[(size_t)b * 12288 + idx];
  }
  if (tid < 32) sgs[tid] = sigG[b * 32 + tid];
  __syncthreads();

  float* cur = R0; float* nxt = R1;
  const int r = tid & 127, hh = tid >> 7;   // hh in {0,1}
  for (int layer = 0; layer < 3; ++layer) {
    const float* wl = w1s[layer];
    float acc[16];
#pragma unroll
    for (int u = 0; u < 16; ++u) acc[u] = 0.f;
    for (int s2 = 0; s2 < 32; ++s2) {
      float rv = cur[r * 33 + s2];
#pragma unroll
      for (int u = 0; u < 16; ++u) acc[u] += rv * wl[s2 * 33 + hh * 16 + u];
    }
#pragma unroll
    for (int u = 0; u < 16; ++u) {
      float v2 = fmaxf(acc[u], 0.f);
      if (layer == 2) v2 = fmaxf(v2 * sgs[hh * 16 + u], 0.f);   // r @ Sigma, relu
      nxt[r * 33 + hh * 16 + u] = v2;
    }
    __syncthreads();
    float* tmp = cur; cur = nxt; nxt = tmp;
  }

  // r4 = relu(cur @ w2[1]) in 32-col chunks; G += relu4 @ Vs
  const int i = tid & 127, h = tid >> 7;
  float gacc[48];
#pragma unroll
  for (int u = 0; u < 48; ++u) gacc[u] = 0.f;
  for (int cc = 0; cc < 4; ++cc) {
    {
      float acc[16];
#pragma unroll
      for (int u = 0; u < 16; ++u) acc[u] = 0.f;
      for (int s2 = 0; s2 < 32; ++s2) {
        float rv = cur[r * 33 + s2];
#pragma unroll
        for (int u = 0; u < 16; ++u) acc[u] += rv * w2s[s2 * 129 + cc * 32 + hh * 16 + u];
      }
#pragma unroll
      for (int u = 0; u < 16; ++u) chnk[r * 33 + hh * 16 + u] = fmaxf(acc[u], 0.f);
    }
    __syncthreads();
    for (int u = 0; u < 32; ++u) {
      float val = chnk[i * 33 + u];
      int vr = cc * 32 + u;
#pragma unroll
      for (int j2 = 0; j2 < 48; ++j2) gacc[j2] += val * vss[vr * 97 + h * 48 + j2];
    }
    __syncthreads();
  }
#pragma unroll
  for (int j2 = 0; j2 < 48; ++j2)
    Gout[(size_t)b * 12288 + i * 96 + h * 48 + j2] = gacc[j2];
}

// ---------------------------------------------------------------------------
// Kernel 5: out(256x256) = G(256x12288) @ weightsO^T(12288x256)
// ---------------------------------------------------------------------------
__global__ __launch_bounds__(256) void ssvd_out_kernel(const float* __restrict__ G,
                                                       const float* __restrict__ wO,
                                                       float* __restrict__ out) {
  __shared__ float Gt[32 * 33];
  __shared__ float Wt[32 * 33];
  const int bi = blockIdx.y, bj = blockIdx.x, tid = threadIdx.x;
  const int tx = tid & 31, ty = tid >> 5;   // ty 0..7
  float acc[4] = {0.f, 0.f, 0.f, 0.f};
  for (int kc = 0; kc < 12288; kc += 32) {
    for (int idx = tid; idx < 1024; idx += 256) {
      int rr = idx >> 5, c = idx & 31;
      Gt[rr * 33 + c] = G[(size_t)(bi * 32 + rr) * 12288 + kc + c];
      Wt[rr * 33 + c] = wO[(size_t)(bj * 32 + rr) * 12288 + kc + c];
    }
    __syncthreads();
    for (int kk = 0; kk < 32; ++kk) {
      float wv = Wt[tx * 33 + kk];
#pragma unroll
      for (int m2 = 0; m2 < 4; ++m2) acc[m2] += Gt[(ty + 8 * m2) * 33 + kk] * wv;
    }
    __syncthreads();
  }
#pragma unroll
  for (int m2 = 0; m2 < 4; ++m2)
    out[(size_t)(bi * 32 + ty + 8 * m2) * 256 + bj * 32 + tx] = acc[m2];
}

// ---------------------------------------------------------------------------
extern "C" void kernel_launch(void* const* d_in, const int* in_sizes, int n_in,
                              void* d_out, int out_size, void* d_ws, size_t ws_size,
                              hipStream_t stream) {
  const float* obs = (const float*)d_in[0];
  const float* w1  = (const float*)d_in[1];
  const float* w2  = (const float*)d_in[2];
  const float* wO  = (const float*)d_in[3];
  const float* c1w = (const float*)d_in[4];
  const float* c1b = (const float*)d_in[5];
  const float* c2w = (const float*)d_in[6];
  const float* c2b = (const float*)d_in[7];
  float* out = (float*)d_out;

  char* ws = (char*)d_ws;
  float* coef = (float*)(ws);                                   //   128 B (30 used)
  float* Us   = (float*)(ws + 1024);                            //  4.19 MB
  float* sg   = (float*)(ws + 1024 + 4194304);                  //   32 KB
  float* Vs   = (float*)(ws + 1024 + 4194304 + 32768);          // 12.58 MB
  float* mats = (float*)(ws + 1024 + 4194304 + 32768 + 12582912); // 16.78 MB
  float* G = mats;  // alias: mats consumed by SVD before net writes G

  ssvd_coef_kernel<<<1, 64, 0, stream>>>(c1w, c1b, c2w, c2b, coef);
  ssvd_mats_kernel<<<16384, 256, 0, stream>>>(obs, coef, mats);
  ssvd_svd_kernel<<<256, 1024, 0, stream>>>(mats, Us, sg, Vs);
  ssvd_net_kernel<<<256, 256, 0, stream>>>(Us, sg, Vs, w1, w2, G);
  ssvd_out_kernel<<<dim3(8, 8), 256, 0, stream>>>(G, wO, out);
}

// Round 4
// 2492.314 us; speedup vs baseline: 6.1488x; 1.4954x over previous
//
#include <hip/hip_runtime.h>
#include <math.h>

#define NSWEEP 16
#define SA 132   // padded LDS column stride (floats); 132*4=528B, 16B-aligned columns

// ---------------------------------------------------------------------------
// Kernel 1: collapse feature-weighting + conv chain into affine coef[29], c0.
// ---------------------------------------------------------------------------
__global__ void ssvd_coef_kernel(const float* __restrict__ c1w, const float* __restrict__ c1b,
                                 const float* __restrict__ c2w, const float* __restrict__ c2b,
                                 float* __restrict__ coefO) {
  if (threadIdx.x != 0 || blockIdx.x != 0) return;
  float cur[6][30], nxt[6][30];
  for (int i = 0; i < 6; ++i)
    for (int d = 0; d < 30; ++d) { cur[i][d] = 0.f; nxt[i][d] = 0.f; }
  const int FS[6] = {5, 5, 3, 8, 6, 2};
  int p = 0;
  for (int f = 0; f < 6; ++f) {
    for (int j = 0; j < FS[f]; ++j) cur[f][p + j] = (float)j;
    p += FS[f];
  }
  int len = 6;
  for (int rep = 0; rep < 3; ++rep) {       // conv1 x3: K=4, stride=2, pad=2
    int ol = len / 2 + 1;
    for (int t = 0; t < ol; ++t) {
      for (int d = 0; d < 30; ++d) {
        float acc = 0.f;
        for (int kk = 0; kk < 4; ++kk) {
          int ix = 2 * t - 2 + kk;
          if (ix >= 0 && ix < len) acc += cur[ix][d] * c1w[kk];
        }
        nxt[t][d] = acc;
      }
      nxt[t][29] += c1b[0];
    }
    for (int t = 0; t < ol; ++t)
      for (int d = 0; d < 30; ++d) cur[t][d] = nxt[t][d];
    len = ol;
  }
  // conv2: K=2, stride=1, pad=0 : len 2 -> 1
  for (int d = 0; d < 30; ++d) coefO[d] = cur[0][d] * c2w[0] + cur[1][d] * c2w[1];
  coefO[29] += c2b[0];
}

// ---------------------------------------------------------------------------
// Kernel 2: mats[b,i,j] = c0 + sum_d coef[d]*obs[b,i,j,d]
// Block covers 256 outputs = 7424 floats = 29696 B (16B-divisible): stage via
// coalesced float4 into LDS, then stride-29 LDS reads.
// ---------------------------------------------------------------------------
__global__ __launch_bounds__(256) void ssvd_mats_kernel(const float* __restrict__ obs,
                                                        const float* __restrict__ coef,
                                                        float* __restrict__ mats) {
  __shared__ __align__(16) float tile[7424];
  __shared__ float cf[32];
  const int tid = threadIdx.x;
  const float4* src = (const float4*)(obs + (size_t)blockIdx.x * 7424);
  float4* dst = (float4*)tile;
  for (int i = tid; i < 1856; i += 256) dst[i] = src[i];
  if (tid < 30) cf[tid] = coef[tid];
  __syncthreads();
  const float* row = tile + tid * 29;
  float acc = cf[29];
#pragma unroll
  for (int d = 0; d < 29; ++d) acc += cf[d] * row[d];
  mats[(size_t)blockIdx.x * 256 + tid] = acc;
}

__device__ __forceinline__ float f4dot(float4 a, float4 b) {
  return a.x * b.x + a.y * b.y + a.z * b.z + a.w * b.w;
}
__device__ __forceinline__ float4 f4rot(float c, float s, float4 a, float4 b) {
  // c*a - s*b
  float4 r;
  r.x = c * a.x - s * b.x; r.y = c * a.y - s * b.y;
  r.z = c * a.z - s * b.z; r.w = c * a.w - s * b.w;
  return r;
}

// ---------------------------------------------------------------------------
// Reduction-free Householder sign extraction for a 128 x ncols matrix with
// (near-)orthonormal columns, column-major stride SA. Destroys M.
// dsgn[j] = sign(R_jj) = -sign(alpha_j)  (LAPACK slarfg convention).
// ---------------------------------------------------------------------------
__device__ __forceinline__ void householder_signs_fast(float* M, int ncols, float* dsgn,
                                                       int tid, int lane, int wid) {
  for (int j = 0; j < ncols; ++j) {
    float alpha = M[j * SA + j];
    float sg = (alpha >= 0.f) ? 1.f : -1.f;
    if (tid == 0) dsgn[j] = -sg;
    float inv = 1.f / (1.f + sg * alpha);
    for (int l = j + 1 + wid; l < ncols; l += 16) {
      float fl = -sg * M[l * SA + j] * inv;
      for (int r = lane; r < 128; r += 64) {
        float vr = M[j * SA + r] + ((r == j) ? sg : 0.f);
        M[l * SA + r] += fl * vr;
      }
    }
    __syncthreads();
  }
}

// ---------------------------------------------------------------------------
// Kernel 3: one-sided Jacobi SVD per 128x128 matrix.
// XOR-tournament with register-resident X columns and migrating Y columns.
// Lazy V: the V-columns are only read/written when a rotation actually
// applies (skip rounds touch just 2 b128 for the A-partner + the dot).
// Outputs: Us (128x32, canonical signs), sigma (32), Vs (128x96, canonical).
// ---------------------------------------------------------------------------
__global__ __launch_bounds__(1024) void ssvd_svd_kernel(const float* __restrict__ mats,
                                                        float* __restrict__ UsG,
                                                        float* __restrict__ sigG,
                                                        float* __restrict__ VsG) {
  __shared__ __align__(16) float A[SA * 128];   // column slots (by column id)
  __shared__ __align__(16) float V[SA * 128];
  __shared__ __align__(16) float W[SA * 32];
  __shared__ float nrmS[128];
  __shared__ double sig[128];
  __shared__ int   perm[128];
  __shared__ float sigs[128];
  __shared__ float dsgn[96];
  __shared__ int   rotFlag[NSWEEP];

  const int b = blockIdx.x;
  const int tid = threadIdx.x;
  const int lane = tid & 63;
  const int wid = tid >> 6;          // 16 waves
  const int g = tid >> 4;            // 0..63 : group (pair processor)
  const int s = tid & 15;            // 0..15 within group
  const int rb = 4 * s;              // rows rb..rb+3 and 64+rb..64+rb+3
  const float* mp = mats + (size_t)b * 16384;

  for (int idx = tid; idx < 16384; idx += 1024) {
    int r = idx >> 7, c = idx & 127;
    A[c * SA + r] = mp[idx];
    V[c * SA + r] = (r == c) ? 1.f : 0.f;
  }
  if (tid < NSWEEP) rotFlag[tid] = 0;
  __syncthreads();

  // initial squared column norms
  {
    int j = tid >> 3, s8 = tid & 7;
    double ss = 0.0;
    for (int r = s8; r < 128; r += 8) { float x = A[j * SA + r]; ss += (double)x * x; }
    for (int off = 1; off < 8; off <<= 1) ss += __shfl_xor(ss, off);
    if (s8 == 0) nrmS[j] = (float)ss;
  }
  __syncthreads();

  // ---- Jacobi sweeps: XOR tournament, lazy V migration ----
  for (int sweep = 0; sweep < NSWEEP; ++sweep) {
    for (int lev = 0; lev < 7; ++lev) {
      const int L = 64 >> lev;
      const int xid = ((g >> lev) << (lev + 1)) | (g & ((1 << lev) - 1));  // bit lev = 0
      int yid = xid | (1 << lev);                                          // m_0 = 1<<lev
      float4 xa0 = *(const float4*)&A[xid * SA + rb];
      float4 xa1 = *(const float4*)&A[xid * SA + 64 + rb];
      float4 xv0 = {0, 0, 0, 0}, xv1 = {0, 0, 0, 0};
      bool xdirty = false;                 // set on first applied rotation this level
      float xn = nrmS[xid];
      float4 ya0 = *(const float4*)&A[yid * SA + rb];
      float4 ya1 = *(const float4*)&A[yid * SA + 64 + rb];
      float4 yv0 = {0, 0, 0, 0}, yv1 = {0, 0, 0, 0};
      float yn = nrmS[yid];
      bool apply = false;

      for (int k = 0; k < L; ++k) {
        float al = f4dot(xa0, ya0) + f4dot(xa1, ya1);
        al += __shfl_xor(al, 1); al += __shfl_xor(al, 2);
        al += __shfl_xor(al, 4); al += __shfl_xor(al, 8);
        apply = (al * al > 1e-12f * xn * yn);
        if (apply) {
          yv0 = *(const float4*)&V[yid * SA + rb];
          yv1 = *(const float4*)&V[yid * SA + 64 + rb];
          if (!xdirty) {
            xv0 = *(const float4*)&V[xid * SA + rb];
            xv1 = *(const float4*)&V[xid * SA + 64 + rb];
            xdirty = true;
          }
          float zeta = (yn - xn) / (2.0f * al);
          float t = copysignf(1.0f, zeta) / (fabsf(zeta) + sqrtf(1.0f + zeta * zeta));
          float cc = 1.0f / sqrtf(1.0f + t * t);
          float sn = cc * t;
          float4 oa0 = xa0, oa1 = xa1, ov0 = xv0, ov1 = xv1;
          xa0 = f4rot(cc, sn, xa0, ya0);  xa1 = f4rot(cc, sn, xa1, ya1);
          ya0 = f4rot(cc, -sn, ya0, oa0); ya1 = f4rot(cc, -sn, ya1, oa1);
          xv0 = f4rot(cc, sn, xv0, yv0);  xv1 = f4rot(cc, sn, xv1, yv1);
          yv0 = f4rot(cc, -sn, yv0, ov0); yv1 = f4rot(cc, -sn, yv1, ov1);
          xn = fmaxf(xn - t * al, 0.f);
          yn = fmaxf(yn + t * al, 0.f);
          if (s == 0) rotFlag[sweep] = 1;
        }
        if (k < L - 1) {
          int nyid = xid ^ ((((k + 1) << 1) | 1) << lev);
          if (apply) {
            *(float4*)&A[yid * SA + rb]      = ya0;
            *(float4*)&A[yid * SA + 64 + rb] = ya1;
            *(float4*)&V[yid * SA + rb]      = yv0;
            *(float4*)&V[yid * SA + 64 + rb] = yv1;
            if (s == 0) nrmS[yid] = yn;
          }
          __syncthreads();
          ya0 = *(const float4*)&A[nyid * SA + rb];
          ya1 = *(const float4*)&A[nyid * SA + 64 + rb];
          yn = nrmS[nyid];
          yid = nyid;
        }
      }
      // level-end: write back only dirty columns
      if (xdirty) {
        *(float4*)&A[xid * SA + rb]      = xa0;
        *(float4*)&A[xid * SA + 64 + rb] = xa1;
        *(float4*)&V[xid * SA + rb]      = xv0;
        *(float4*)&V[xid * SA + 64 + rb] = xv1;
        if (s == 0) nrmS[xid] = xn;
      }
      if (apply) {   // last round rotated: Y regs ahead of LDS
        *(float4*)&A[yid * SA + rb]      = ya0;
        *(float4*)&A[yid * SA + 64 + rb] = ya1;
        *(float4*)&V[yid * SA + rb]      = yv0;
        *(float4*)&V[yid * SA + 64 + rb] = yv1;
        if (s == 0) nrmS[yid] = yn;
      }
      __syncthreads();
    }
    if (rotFlag[sweep] == 0) break;   // converged: full sweep with no rotation
  }

  // ---- column norms (sigma), fresh double recompute ----
  {
    int j = tid >> 3, s8 = tid & 7;
    double ss = 0.0;
    for (int r = s8; r < 128; r += 8) { float x = A[j * SA + r]; ss += (double)x * x; }
    for (int off = 1; off < 8; off <<= 1) ss += __shfl_xor(ss, off);
    if (s8 == 0) sig[j] = sqrt(ss);
  }
  __syncthreads();

  // ---- rank-sort descending ----
  if (tid < 128) {
    double sj = sig[tid];
    int rk = 0;
    for (int i = 0; i < 128; ++i) {
      double si = sig[i];
      if (si > sj || (si == sj && i < tid)) ++rk;
    }
    perm[rk] = tid;
    sigs[rk] = (float)sj;
  }
  __syncthreads();

  // ---- W = Uk (top-32 normalized columns) ----
  for (int idx = tid; idx < 128 * 32; idx += 1024) {
    int t = idx >> 7, r = idx & 127;
    W[t * SA + r] = A[perm[t] * SA + r] / sigs[t];
  }
  __syncthreads();

  householder_signs_fast(W, 32, dsgn, tid, lane, wid);

  // Us = Uk * D   (A still intact)
  for (int idx = tid; idx < 4096; idx += 1024) {
    int r = idx >> 5, t = idx & 31;
    UsG[((size_t)b * 128 + r) * 32 + t] = dsgn[t] * A[perm[t] * SA + r] / sigs[t];
  }
  if (tid < 32) sigG[b * 32 + tid] = sigs[tid];
  __syncthreads();

  // ---- M = Vr^T (bottom-96 right singular vectors as columns), reuse A ----
  for (int idx = tid; idx < 128 * 96; idx += 1024) {
    int t = idx >> 7, r = idx & 127;
    A[t * SA + r] = V[perm[32 + t] * SA + r];
  }
  __syncthreads();

  householder_signs_fast(A, 96, dsgn, tid, lane, wid);

  // Vs = Vr^T * D  (V still intact)
  for (int idx = tid; idx < 12288; idx += 1024) {
    int r = idx / 96, ss2 = idx % 96;
    VsG[((size_t)b * 128 + r) * 96 + ss2] = dsgn[ss2] * V[perm[32 + ss2] * SA + r];
  }
}

// ---------------------------------------------------------------------------
// Kernel 4: per-matrix relu network -> G[b] = (r @ Vs) flattened (128*96)
// ---------------------------------------------------------------------------
__global__ __launch_bounds__(256) void ssvd_net_kernel(const float* __restrict__ UsG,
                                                       const float* __restrict__ sigG,
                                                       const float* __restrict__ VsG,
                                                       const float* __restrict__ w1g,
                                                       const float* __restrict__ w2g,
                                                       float* __restrict__ Gout) {
  __shared__ float R0[128 * 33];
  __shared__ float R1[128 * 33];
  __shared__ float w1s[3][32 * 33];
  __shared__ float w2s[32 * 129];
  __shared__ float vss[128 * 97];
  __shared__ float chnk[128 * 33];
  __shared__ float sgs[32];

  const int b = blockIdx.x, tid = threadIdx.x;

  for (int idx = tid; idx < 4096; idx += 256) {
    int r = idx >> 5, c = idx & 31;
    R0[r * 33 + c] = UsG[((size_t)b * 128 + r) * 32 + c];
  }
  for (int idx = tid; idx < 3072; idx += 256) {
    int i = idx >> 10, rem = idx & 1023, s = rem >> 5, c = rem & 31;
    w1s[i][s * 33 + c] = w1g[idx];
  }
  for (int idx = tid; idx < 4096; idx += 256) {   // weights2[1] only
    int s = idx >> 7, c = idx & 127;
    w2s[s * 129 + c] = w2g[32 * 128 + idx];
  }
  for (int idx = tid; idx < 12288; idx += 256) {
    int r = idx / 96, c = idx % 96;
    vss[r * 97 + c] = VsG[(size_t)b * 12288 + idx];
  }
  if (tid < 32) sgs[tid] = sigG[b * 32 + tid];
  __syncthreads();

  float* cur = R0; float* nxt = R1;
  const int r = tid & 127, hh = tid >> 7;   // hh in {0,1}
  for (int layer = 0; layer < 3; ++layer) {
    const float* wl = w1s[layer];
    float acc[16];
#pragma unroll
    for (int u = 0; u < 16; ++u) acc[u] = 0.f;
    for (int s2 = 0; s2 < 32; ++s2) {
      float rv = cur[r * 33 + s2];
#pragma unroll
      for (int u = 0; u < 16; ++u) acc[u] += rv * wl[s2 * 33 + hh * 16 + u];
    }
#pragma unroll
    for (int u = 0; u < 16; ++u) {
      float v2 = fmaxf(acc[u], 0.f);
      if (layer == 2) v2 = fmaxf(v2 * sgs[hh * 16 + u], 0.f);   // r @ Sigma, relu
      nxt[r * 33 + hh * 16 + u] = v2;
    }
    __syncthreads();
    float* tmp = cur; cur = nxt; nxt = tmp;
  }

  // r4 = relu(cur @ w2[1]) in 32-col chunks; G += relu4 @ Vs
  const int i = tid & 127, h = tid >> 7;
  float gacc[48];
#pragma unroll
  for (int u = 0; u < 48; ++u) gacc[u] = 0.f;
  for (int cc = 0; cc < 4; ++cc) {
    {
      float acc[16];
#pragma unroll
      for (int u = 0; u < 16; ++u) acc[u] = 0.f;
      for (int s2 = 0; s2 < 32; ++s2) {
        float rv = cur[r * 33 + s2];
#pragma unroll
        for (int u = 0; u < 16; ++u) acc[u] += rv * w2s[s2 * 129 + cc * 32 + hh * 16 + u];
      }
#pragma unroll
      for (int u = 0; u < 16; ++u) chnk[r * 33 + hh * 16 + u] = fmaxf(acc[u], 0.f);
    }
    __syncthreads();
    for (int u = 0; u < 32; ++u) {
      float val = chnk[i * 33 + u];
      int vr = cc * 32 + u;
#pragma unroll
      for (int j2 = 0; j2 < 48; ++j2) gacc[j2] += val * vss[vr * 97 + h * 48 + j2];
    }
    __syncthreads();
  }
#pragma unroll
  for (int j2 = 0; j2 < 48; ++j2)
    Gout[(size_t)b * 12288 + i * 96 + h * 48 + j2] = gacc[j2];
}

// ---------------------------------------------------------------------------
// Kernel 5a: split-K GEMM partials. out = G(256x12288) @ wO^T(12288x256).
// Grid (4,4,16): 64x64 output tile, K-slice of 768 per z. k-major LDS tiles
// so the inner loop is 2 x ds_read_b128 per 16 FMA. 4x4 register tile/thread.
// ---------------------------------------------------------------------------
__global__ __launch_bounds__(256) void ssvd_out1_kernel(const float* __restrict__ G,
                                                        const float* __restrict__ wO,
                                                        float* __restrict__ partial) {
  __shared__ __align__(16) float Gt[64][68];
  __shared__ __align__(16) float Wt[64][68];
  const int tid = threadIdx.x;
  const int tx = tid & 15, ty = tid >> 4;
  const int bj = blockIdx.x, bi = blockIdx.y, bz = blockIdx.z;
  const int r0 = tid >> 2;              // 0..63
  const int ku = (tid & 3) * 16;        // k sub-offset
  float4 acc[4] = {{0,0,0,0},{0,0,0,0},{0,0,0,0},{0,0,0,0}};
  const float* gbase = G  + (size_t)(bi * 64 + r0) * 12288;
  const float* wbase = wO + (size_t)(bj * 64 + r0) * 12288;
  for (int sc = 0; sc < 12; ++sc) {
    const int kc0 = bz * 768 + sc * 64;
    __syncthreads();
#pragma unroll
    for (int u = 0; u < 4; ++u) {
      int kl = ku + u * 4;
      float4 gv = *(const float4*)(gbase + kc0 + kl);
      float4 wv = *(const float4*)(wbase + kc0 + kl);
      Gt[kl + 0][r0] = gv.x; Gt[kl + 1][r0] = gv.y; Gt[kl + 2][r0] = gv.z; Gt[kl + 3][r0] = gv.w;
      Wt[kl + 0][r0] = wv.x; Wt[kl + 1][r0] = wv.y; Wt[kl + 2][r0] = wv.z; Wt[kl + 3][r0] = wv.w;
    }
    __syncthreads();
    for (int k = 0; k < 64; ++k) {
      float4 gv = *(const float4*)&Gt[k][ty * 4];
      float4 wv = *(const float4*)&Wt[k][tx * 4];
      acc[0].x += gv.x * wv.x; acc[0].y += gv.x * wv.y; acc[0].z += gv.x * wv.z; acc[0].w += gv.x * wv.w;
      acc[1].x += gv.y * wv.x; acc[1].y += gv.y * wv.y; acc[1].z += gv.y * wv.z; acc[1].w += gv.y * wv.w;
      acc[2].x += gv.z * wv.x; acc[2].y += gv.z * wv.y; acc[2].z += gv.z * wv.z; acc[2].w += gv.z * wv.w;
      acc[3].x += gv.w * wv.x; acc[3].y += gv.w * wv.y; acc[3].z += gv.w * wv.z; acc[3].w += gv.w * wv.w;
    }
  }
#pragma unroll
  for (int a = 0; a < 4; ++a) {
    size_t o = (size_t)bz * 65536 + (size_t)(bi * 64 + ty * 4 + a) * 256 + bj * 64 + tx * 4;
    *(float4*)&partial[o] = acc[a];
  }
}

// ---------------------------------------------------------------------------
// Kernel 5b: deterministic reduce of the 16 K-slices.
// ---------------------------------------------------------------------------
__global__ __launch_bounds__(256) void ssvd_out2_kernel(const float* __restrict__ partial,
                                                        float* __restrict__ out) {
  int idx = blockIdx.x * 256 + threadIdx.x;
  float s = 0.f;
#pragma unroll
  for (int z = 0; z < 16; ++z) s += partial[z * 65536 + idx];
  out[idx] = s;
}

// ---------------------------------------------------------------------------
extern "C" void kernel_launch(void* const* d_in, const int* in_sizes, int n_in,
                              void* d_out, int out_size, void* d_ws, size_t ws_size,
                              hipStream_t stream) {
  const float* obs = (const float*)d_in[0];
  const float* w1  = (const float*)d_in[1];
  const float* w2  = (const float*)d_in[2];
  const float* wO  = (const float*)d_in[3];
  const float* c1w = (const float*)d_in[4];
  const float* c1b = (const float*)d_in[5];
  const float* c2w = (const float*)d_in[6];
  const float* c2b = (const float*)d_in[7];
  float* out = (float*)d_out;

  char* ws = (char*)d_ws;
  float* coef = (float*)(ws);                                   //   128 B (30 used)
  float* Us   = (float*)(ws + 1024);                            //  4.19 MB
  float* sg   = (float*)(ws + 1024 + 4194304);                  //   32 KB
  float* Vs   = (float*)(ws + 1024 + 4194304 + 32768);          // 12.58 MB
  float* mats = (float*)(ws + 1024 + 4194304 + 32768 + 12582912); // 16.78 MB
  float* G = mats;       // alias: mats consumed by SVD before net writes G
  float* partial = Us;   // alias: Us dead after net; 16*65536*4 = 4.19 MB exact

  ssvd_coef_kernel<<<1, 64, 0, stream>>>(c1w, c1b, c2w, c2b, coef);
  ssvd_mats_kernel<<<16384, 256, 0, stream>>>(obs, coef, mats);
  ssvd_svd_kernel<<<256, 1024, 0, stream>>>(mats, Us, sg, Vs);
  ssvd_net_kernel<<<256, 256, 0, stream>>>(Us, sg, Vs, w1, w2, G);
  ssvd_out1_kernel<<<dim3(4, 4, 16), 256, 0, stream>>>(G, wO, partial);
  ssvd_out2_kernel<<<256, 256, 0, stream>>>(partial, out);
}